// Round 1
// baseline (110.992 us; speedup 1.0000x reference)
//
#include <hip/hip_runtime.h>
#include <hip/hip_bf16.h>
#include <cstdint>
#include <cstddef>

#define NUM_CLASS 32
#define D_DIM 256
#define PIX_PER_IMG 25600          // 160*160
#define N_B 8
#define TILE_PX 64
#define TILES_PER_IMG (PIX_PER_IMG / TILE_PX)   // 400
#define N_TILES (N_B * TILES_PER_IMG)           // 3200
#define BLOCK_THREADS 512
#define MAX_GRID 640

typedef __attribute__((ext_vector_type(4))) float  f32x4;
typedef __attribute__((ext_vector_type(8))) __bf16 bf16x8;
typedef unsigned short ushort8 __attribute__((ext_vector_type(8)));
typedef unsigned int   uint4v  __attribute__((ext_vector_type(4)));
typedef unsigned int   uint2v  __attribute__((ext_vector_type(2)));

// RNE float -> bf16 bits (finite inputs only)
__device__ __forceinline__ unsigned short f2bf(float x) {
    unsigned u = __builtin_bit_cast(unsigned, x);
    unsigned r = (u + 0x7fffu + ((u >> 16) & 1u)) >> 16;
    return (unsigned short)r;
}

// swizzled byte offset inside the [256][64] bf16 LDS tile (row stride 128B)
// XOR bits 4..6 with (d&7) -> spreads the d-major ds_read_b128 across banks
__device__ __forceinline__ int tile_off(int d, int p) {
    return d * 128 + ((p * 2) ^ ((d & 7) << 4));
}

__global__ __launch_bounds__(BLOCK_THREADS)
void emb_main(const float* __restrict__ feat, const float* __restrict__ mask,
              float* __restrict__ part, float* __restrict__ npart, int G)
{
    __shared__ __align__(16) unsigned char tile[D_DIM * 128]; // 32KB bf16, swizzled
    __shared__ __align__(16) f32x4 ssq[8 * 16];               // 2KB
    __shared__ unsigned long long cmask[NUM_CLASS];           // per-class pixel bitmap
    __shared__ __align__(16) unsigned short inv_bf[TILE_PX];  // bf16 invnorm per pixel
    __shared__ int ncnt[NUM_CLASS];

    const int t    = threadIdx.x;
    const int lane = t & 63;
    const int wave = t >> 6;          // 0..7
    const int blk  = blockIdx.x;

    if (t < NUM_CLASS) ncnt[t] = 0;

    f32x4 acc[2][2] = {};             // [mtile(class16)][ntile(d16)], persists over tiles

    const int pg = t & 15;            // pixel group (4 px)
    const int rg = t >> 4;            // row group 0..31

    for (int ti = blk; ti < N_TILES; ti += G) {
        __syncthreads();              // previous tile fully consumed (also covers ncnt init)
        const int b  = ti / TILES_PER_IMG;
        const int p0 = (ti % TILES_PER_IMG) * TILE_PX;

        // ---- stage feature tile: 256 d x 64 px, float4 coalesced ----
        const float* fbase = feat + (size_t)b * D_DIM * PIX_PER_IMG + p0 + pg * 4;
        f32x4 ss = {0.f, 0.f, 0.f, 0.f};
        #pragma unroll
        for (int k = 0; k < 8; ++k) {
            const int d = rg + 32 * k;
            f32x4 v = *(const f32x4*)(fbase + (size_t)d * PIX_PER_IMG);
            ss += v * v;
            uint2v hw;
            hw.x = (unsigned)f2bf(v.x) | ((unsigned)f2bf(v.y) << 16);
            hw.y = (unsigned)f2bf(v.z) | ((unsigned)f2bf(v.w) << 16);
            *(uint2v*)(tile + tile_off(d, pg * 4)) = hw;
        }
        // reduce ssq across the 4 row-groups sharing pg inside this wave
        ss.x += __shfl_down(ss.x, 32); ss.y += __shfl_down(ss.y, 32);
        ss.z += __shfl_down(ss.z, 32); ss.w += __shfl_down(ss.w, 32);
        ss.x += __shfl_down(ss.x, 16); ss.y += __shfl_down(ss.y, 16);
        ss.z += __shfl_down(ss.z, 16); ss.w += __shfl_down(ss.w, 16);
        if (lane < 16) ssq[wave * 16 + lane] = ss;

        // ---- stage mask: per-class 64-pixel ballots (one row per wave per pass) ----
        {
            const float* mbase = mask + (size_t)b * NUM_CLASS * PIX_PER_IMG + p0 + lane;
            #pragma unroll
            for (int q = 0; q < 4; ++q) {
                const int c = wave + 8 * q;
                const float mv = mbase[(size_t)c * PIX_PER_IMG];
                unsigned long long bal = __ballot(mv > 0.5f);
                if (lane == 0) { cmask[c] = bal; ncnt[c] += __popcll(bal); }
            }
        }
        __syncthreads();              // tile, ssq, cmask ready

        // ---- per-pixel inverse norm ----
        if (t < TILE_PX) {
            const float* sf = (const float*)ssq;  // [8][64] flat
            float tot = 0.f;
            #pragma unroll
            for (int w = 0; w < 8; ++w) tot += sf[w * 64 + t];
            const float invn = 1.0f / fmaxf(sqrtf(tot), 1e-8f);
            inv_bf[t] = f2bf(invn);
        }
        __syncthreads();              // inv_bf ready

        // ---- MFMA: s[32 classes][32 d per wave] += maskw^T x U ----
        const int cl = lane & 15;     // col within 16-wide tile
        const int kg = lane >> 4;     // 0..3 k-group
        const int dbase = wave * 32;
        const unsigned long long cm0 = cmask[cl];
        const unsigned long long cm1 = cmask[16 + cl];
        #pragma unroll
        for (int ks = 0; ks < 2; ++ks) {
            const int kp0 = ks * 32 + kg * 8;
            const ushort8 iv = *(const ushort8*)((const char*)inv_bf + kp0 * 2);
            ushort8 a0, a1;
            #pragma unroll
            for (int i = 0; i < 8; ++i) {
                const int kp = kp0 + i;
                a0[i] = (unsigned short)(((cm0 >> kp) & 1ull) ? iv[i] : 0);
                a1[i] = (unsigned short)(((cm1 >> kp) & 1ull) ? iv[i] : 0);
            }
            const bf16x8 ba0 = __builtin_bit_cast(bf16x8, a0);
            const bf16x8 ba1 = __builtin_bit_cast(bf16x8, a1);
            const uint4v rb0 = *(const uint4v*)(tile + tile_off(dbase + cl, kp0));
            const uint4v rb1 = *(const uint4v*)(tile + tile_off(dbase + 16 + cl, kp0));
            const bf16x8 bb0 = __builtin_bit_cast(bf16x8, rb0);
            const bf16x8 bb1 = __builtin_bit_cast(bf16x8, rb1);
            acc[0][0] = __builtin_amdgcn_mfma_f32_16x16x32_bf16(ba0, bb0, acc[0][0], 0, 0, 0);
            acc[0][1] = __builtin_amdgcn_mfma_f32_16x16x32_bf16(ba0, bb1, acc[0][1], 0, 0, 0);
            acc[1][0] = __builtin_amdgcn_mfma_f32_16x16x32_bf16(ba1, bb0, acc[1][0], 0, 0, 0);
            acc[1][1] = __builtin_amdgcn_mfma_f32_16x16x32_bf16(ba1, bb1, acc[1][1], 0, 0, 0);
        }
    }

    // ---- write per-block partial s (no atomics) ----
    {
        float* myout = part + (size_t)blk * (NUM_CLASS * D_DIM);
        const int cl = lane & 15;
        const int kg = lane >> 4;
        const int dbase = wave * 32;
        #pragma unroll
        for (int mt = 0; mt < 2; ++mt)
            #pragma unroll
            for (int nt = 0; nt < 2; ++nt)
                #pragma unroll
                for (int r = 0; r < 4; ++r) {
                    const int c = mt * 16 + kg * 4 + r;   // C/D: row=(lane>>4)*4+reg
                    const int d = dbase + nt * 16 + cl;   //      col=lane&15
                    myout[c * D_DIM + d] = acc[mt][nt][r];
                }
    }
    __syncthreads();
    if (t < NUM_CLASS) npart[(size_t)blk * NUM_CLASS + t] = (float)ncnt[t];
}

__global__ void emb_reduce(const float* __restrict__ part, const float* __restrict__ npart,
                           float* __restrict__ cls, int G)
{
    const int c = blockIdx.x;         // class
    const int t = threadIdx.x;        // d (0..255)
    const int lane = t & 63, wave = t >> 6;
    float s = 0.f;
    #pragma unroll 8
    for (int g = 0; g < G; ++g) s += part[(size_t)g * (NUM_CLASS * D_DIM) + c * D_DIM + t];
    float nsum = 0.f;
    for (int g = t; g < G; g += 256) nsum += npart[(size_t)g * NUM_CLASS + c];
    float s2 = s * s;
    #pragma unroll
    for (int off = 32; off > 0; off >>= 1) {
        s2   += __shfl_down(s2, off);
        nsum += __shfl_down(nsum, off);
    }
    __shared__ float rs2[4], rn[4];
    if (lane == 0) { rs2[wave] = s2; rn[wave] = nsum; }
    __syncthreads();
    if (t == 0) {
        const float S2 = rs2[0] + rs2[1] + rs2[2] + rs2[3];
        const float N  = rn[0] + rn[1] + rn[2] + rn[3];
        const float pair = 0.5f * (S2 - N);
        const float den  = 0.5f * N * (N + 1.0f);
        cls[c] = (N > 0.f) ? (pair / fmaxf(den, 1.0f)) : 0.f;
    }
}

__global__ void emb_final(const float* __restrict__ cls, float* __restrict__ out)
{
    const int t = threadIdx.x;        // 64 threads
    float v = (t < NUM_CLASS) ? cls[t] : 0.f;
    #pragma unroll
    for (int off = 32; off > 0; off >>= 1) v += __shfl_down(v, off);
    if (t == 0) {
        const float emb = v / (float)NUM_CLASS;
        out[0] = 1.0f * expf(-2.0f * emb);   // ALPHA * exp(-GAMMA * emb)
    }
}

extern "C" void kernel_launch(void* const* d_in, const int* in_sizes, int n_in,
                              void* d_out, int out_size, void* d_ws, size_t ws_size,
                              hipStream_t stream)
{
    const float* feat = (const float*)d_in[0];
    const float* mask = (const float*)d_in[1];
    float* out = (float*)d_out;

    // ws layout: [G * 8192 floats partial s][G * 32 floats partial n][32 floats cls]
    const size_t per_blk = (size_t)(NUM_CLASS * D_DIM + NUM_CLASS) * sizeof(float);
    int G = MAX_GRID;
    size_t need = (size_t)G * per_blk + NUM_CLASS * sizeof(float);
    if (ws_size < need) {
        size_t g = (ws_size > NUM_CLASS * sizeof(float))
                       ? (ws_size - NUM_CLASS * sizeof(float)) / per_blk : 1;
        if (g < 1) g = 1;
        if (g > MAX_GRID) g = MAX_GRID;
        G = (int)g;
    }
    float* part  = (float*)d_ws;
    float* npart = part + (size_t)G * (NUM_CLASS * D_DIM);
    float* cls   = npart + (size_t)G * NUM_CLASS;

    emb_main<<<G, BLOCK_THREADS, 0, stream>>>(feat, mask, part, npart, G);
    emb_reduce<<<NUM_CLASS, 256, 0, stream>>>(part, npart, cls, G);
    emb_final<<<1, 64, 0, stream>>>(cls, out);
}

// Round 2
// 52.314 us; speedup vs baseline: 2.1216x; 2.1216x over previous
//
#include <hip/hip_runtime.h>
#include <hip/hip_bf16.h>
#include <cstdint>
#include <cstddef>

#define NUM_CLASS 32
#define D_DIM 256
#define PIX_PER_IMG 25600          // 160*160
#define TILE_PX 64
#define TILES_PER_IMG 400          // 25600/64
#define N_TILES 3200               // 8 images * 400
#define BLOCK_THREADS 512
#define MAX_GRID 256

typedef __attribute__((ext_vector_type(4))) float  f32x4;
typedef __attribute__((ext_vector_type(8))) __bf16 bf16x8;
typedef unsigned short ushort8 __attribute__((ext_vector_type(8)));

// RNE float -> bf16 bits (finite inputs only)
__device__ __forceinline__ unsigned short f2bf(float x) {
    unsigned u = __builtin_bit_cast(unsigned, x);
    unsigned r = (u + 0x7fffu + ((u >> 16) & 1u)) >> 16;
    return (unsigned short)r;
}

__device__ __forceinline__ ushort8 pack_bf8(f32x4 a, f32x4 b) {
    ushort8 r;
    r[0] = f2bf(a.x); r[1] = f2bf(a.y); r[2] = f2bf(a.z); r[3] = f2bf(a.w);
    r[4] = f2bf(b.x); r[5] = f2bf(b.y); r[6] = f2bf(b.z); r[7] = f2bf(b.w);
    return r;
}

// async 16B/lane global -> LDS (dest is wave-uniform base + lane*16)
__device__ __forceinline__ void gll16(const float* src, float* ldst) {
    __builtin_amdgcn_global_load_lds(
        (const __attribute__((address_space(1))) float*)src,
        (__attribute__((address_space(3))) float*)ldst, 16, 0, 0);
}

// swizzled f32x4 read: rows are 256B (64 px); slot(g,row) = g ^ ((row&7)<<1)
#define SWZROW(base, row, g) \
    (*(const f32x4*)((const char*)(base) + (row) * 256 + ((((g) ^ (((row) & 7) << 1))) << 4)))

__global__ __launch_bounds__(BLOCK_THREADS)
void emb_main(const float* __restrict__ feat, const float* __restrict__ mask,
              float* __restrict__ part, float* __restrict__ npart, int G)
{
    __shared__ __align__(16) float ftile[2][D_DIM][TILE_PX];       // 128 KB
    __shared__ __align__(16) float mtile[2][NUM_CLASS][TILE_PX];   // 16 KB
    __shared__ __align__(16) float ssq_s[8][TILE_PX];              // 2 KB
    __shared__ __align__(16) unsigned short inv_bf[TILE_PX];       // 128 B

    const int t = threadIdx.x;
    const int lane = t & 63;
    const int wave = t >> 6;           // 0..7
    const int blk  = blockIdx.x;
    const int lh = lane >> 4;          // 0..3
    const int ll = lane & 15;          // 0..15

    const int nt = (blk < N_TILES) ? ((N_TILES - 1 - blk) / G + 1) : 0;

    f32x4 acc[2][2] = {};              // [class-tile][d-tile]
    float ncA = 0.f, ncB = 0.f;        // wave-0 class pixel counts (cl, 16+cl)

    // ---- async stage of one tile (9 gll per wave: 8 feat + 1 mask) ----
    auto stage = [&](int ti, int buf) {
        const int b  = ti / TILES_PER_IMG;
        const int p0 = (ti - b * TILES_PER_IMG) * TILE_PX;
        const float* fb = feat + (size_t)b * ((size_t)D_DIM * PIX_PER_IMG) + p0;
        #pragma unroll
        for (int j = 0; j < 8; ++j) {
            const int dr = wave * 32 + j * 4;      // 4 rows per instr
            const int d  = dr + lh;
            const int g  = ll ^ ((d & 7) << 1);    // pre-swizzled source px-group
            gll16(fb + (size_t)d * PIX_PER_IMG + g * 4, &ftile[buf][dr][0]);
        }
        const int c  = wave * 4 + lh;
        const int gm = ll ^ ((c & 7) << 1);
        gll16(mask + (size_t)b * (NUM_CLASS * PIX_PER_IMG) + (size_t)c * PIX_PER_IMG + p0 + gm * 4,
              &mtile[buf][wave * 4][0]);
    };

    if (nt > 0) stage(blk, 0);

    const int rg   = wave * 4 + lh;                  // row-group 0..31 (P1)
    const int soff = ((ll ^ ((rg & 7) << 1)) << 4);  // constant swizzle byte off (P1)

    for (int i = 0; i < nt; ++i) {
        const int buf = i & 1;
        if (i + 1 < nt) {
            stage(blk + (i + 1) * G, buf ^ 1);
            asm volatile("s_waitcnt vmcnt(9)" ::: "memory");   // tile i staged; i+1 in flight
        } else {
            asm volatile("s_waitcnt vmcnt(0)" ::: "memory");
        }
        __builtin_amdgcn_s_barrier();
        __builtin_amdgcn_sched_barrier(0);

        // ---- P1: per-pixel sum of squares from LDS f32 tile ----
        const char* fbase = (const char*)&ftile[buf][0][0];
        f32x4 ss = {0.f, 0.f, 0.f, 0.f};
        #pragma unroll
        for (int k = 0; k < 8; ++k) {
            const int d = rg + 32 * k;
            const f32x4 v = *(const f32x4*)(fbase + d * 256 + soff);
            ss += v * v;
        }
        ss.x += __shfl_down(ss.x, 32); ss.y += __shfl_down(ss.y, 32);
        ss.z += __shfl_down(ss.z, 32); ss.w += __shfl_down(ss.w, 32);
        ss.x += __shfl_down(ss.x, 16); ss.y += __shfl_down(ss.y, 16);
        ss.z += __shfl_down(ss.z, 16); ss.w += __shfl_down(ss.w, 16);
        if (lane < 16) *(f32x4*)&ssq_s[wave][lane * 4] = ss;
        __builtin_amdgcn_sched_barrier(0);
        asm volatile("s_waitcnt lgkmcnt(0)" ::: "memory");
        __builtin_amdgcn_s_barrier();
        __builtin_amdgcn_sched_barrier(0);

        // ---- P2: inverse norm per pixel (wave 0) ----
        if (t < TILE_PX) {
            float tot = 0.f;
            #pragma unroll
            for (int w = 0; w < 8; ++w) tot += ssq_s[w][t];
            inv_bf[t] = f2bf(1.0f / fmaxf(sqrtf(tot), 1e-8f));
        }
        __builtin_amdgcn_sched_barrier(0);
        asm volatile("s_waitcnt lgkmcnt(0)" ::: "memory");
        __builtin_amdgcn_s_barrier();
        __builtin_amdgcn_sched_barrier(0);

        // ---- P3: build A (mask*inv) and B (bf16 U) frags, 8 MFMA ----
        const char* mbase = (const char*)&mtile[buf][0][0];
        const int dbase = wave * 32;
        #pragma unroll
        for (int ks = 0; ks < 2; ++ks) {
            const int kp0 = ks * 32 + lh * 8;     // pixel start for this lane's k-group
            const int g0  = kp0 >> 2;
            const ushort8 iv = *(const ushort8*)(inv_bf + kp0);

            const f32x4 ma0 = SWZROW(mbase, ll,      g0);
            const f32x4 ma1 = SWZROW(mbase, ll,      g0 + 1);
            const f32x4 mb0 = SWZROW(mbase, 16 + ll, g0);
            const f32x4 mb1 = SWZROW(mbase, 16 + ll, g0 + 1);
            ushort8 a0, a1;
            #pragma unroll
            for (int q = 0; q < 4; ++q) {
                a0[q]     = (ma0[q] > 0.5f) ? iv[q]     : (unsigned short)0;
                a0[q + 4] = (ma1[q] > 0.5f) ? iv[q + 4] : (unsigned short)0;
                a1[q]     = (mb0[q] > 0.5f) ? iv[q]     : (unsigned short)0;
                a1[q + 4] = (mb1[q] > 0.5f) ? iv[q + 4] : (unsigned short)0;
            }
            if (wave == 0) {
                ncA += ma0[0] + ma0[1] + ma0[2] + ma0[3] + ma1[0] + ma1[1] + ma1[2] + ma1[3];
                ncB += mb0[0] + mb0[1] + mb0[2] + mb0[3] + mb1[0] + mb1[1] + mb1[2] + mb1[3];
            }

            const f32x4 f00 = SWZROW(fbase, dbase + ll,      g0);
            const f32x4 f01 = SWZROW(fbase, dbase + ll,      g0 + 1);
            const f32x4 f10 = SWZROW(fbase, dbase + 16 + ll, g0);
            const f32x4 f11 = SWZROW(fbase, dbase + 16 + ll, g0 + 1);

            const bf16x8 ba0 = __builtin_bit_cast(bf16x8, a0);
            const bf16x8 ba1 = __builtin_bit_cast(bf16x8, a1);
            const bf16x8 bb0 = __builtin_bit_cast(bf16x8, pack_bf8(f00, f01));
            const bf16x8 bb1 = __builtin_bit_cast(bf16x8, pack_bf8(f10, f11));

            acc[0][0] = __builtin_amdgcn_mfma_f32_16x16x32_bf16(ba0, bb0, acc[0][0], 0, 0, 0);
            acc[0][1] = __builtin_amdgcn_mfma_f32_16x16x32_bf16(ba0, bb1, acc[0][1], 0, 0, 0);
            acc[1][0] = __builtin_amdgcn_mfma_f32_16x16x32_bf16(ba1, bb0, acc[1][0], 0, 0, 0);
            acc[1][1] = __builtin_amdgcn_mfma_f32_16x16x32_bf16(ba1, bb1, acc[1][1], 0, 0, 0);
        }
        __builtin_amdgcn_sched_barrier(0);
        asm volatile("s_waitcnt lgkmcnt(0)" ::: "memory");
        __builtin_amdgcn_s_barrier();   // all waves done reading buf -> next stage may overwrite
        __builtin_amdgcn_sched_barrier(0);
    }

    // ---- per-block partial s (C/D layout: col=lane&15, row=(lane>>4)*4+reg) ----
    {
        float* myout = part + (size_t)blk * (NUM_CLASS * D_DIM);
        const int dbase = wave * 32;
        #pragma unroll
        for (int mt = 0; mt < 2; ++mt)
            #pragma unroll
            for (int ntile = 0; ntile < 2; ++ntile)
                #pragma unroll
                for (int r = 0; r < 4; ++r) {
                    const int c = mt * 16 + lh * 4 + r;
                    const int d = dbase + ntile * 16 + ll;
                    myout[c * D_DIM + d] = acc[mt][ntile][r];
                }
    }
    ncA += __shfl_xor(ncA, 16); ncA += __shfl_xor(ncA, 32);
    ncB += __shfl_xor(ncB, 16); ncB += __shfl_xor(ncB, 32);
    if (wave == 0 && lane < 16) {
        npart[(size_t)blk * NUM_CLASS + lane]      = ncA;
        npart[(size_t)blk * NUM_CLASS + 16 + lane] = ncB;
    }
}

__global__ __launch_bounds__(1024)
void emb_reduce(const float* __restrict__ part, const float* __restrict__ npart,
                float* __restrict__ cls, int G)
{
    const int c = blockIdx.x;          // class
    const int t = threadIdx.x;
    const int d = t & 255, gs = t >> 8;        // d-slot, g-stripe 0..3
    float s = 0.f;
    #pragma unroll 8
    for (int g = gs; g < G; g += 4)
        s += part[(size_t)g * (NUM_CLASS * D_DIM) + c * D_DIM + d];
    __shared__ float red[4][256];
    red[gs][d] = s;
    float nsum = 0.f;
    for (int g = t; g < G; g += 1024) nsum += npart[(size_t)g * NUM_CLASS + c];
    __syncthreads();
    float s2 = 0.f;
    if (t < 256) {
        const float tot = red[0][t] + red[1][t] + red[2][t] + red[3][t];
        s2 = tot * tot;
    }
    const int lane = t & 63, wave = t >> 6;
    #pragma unroll
    for (int off = 32; off > 0; off >>= 1) {
        s2   += __shfl_down(s2, off);
        nsum += __shfl_down(nsum, off);
    }
    __shared__ float rs[16], rn[16];
    if (lane == 0) { rs[wave] = s2; rn[wave] = nsum; }
    __syncthreads();
    if (t == 0) {
        float S2 = 0.f, N = 0.f;
        #pragma unroll
        for (int w = 0; w < 16; ++w) { S2 += rs[w]; N += rn[w]; }
        const float pair = 0.5f * (S2 - N);
        const float den  = 0.5f * N * (N + 1.0f);
        cls[c] = (N > 0.f) ? (pair / fmaxf(den, 1.0f)) : 0.f;
    }
}

__global__ void emb_final(const float* __restrict__ cls, float* __restrict__ out)
{
    const int t = threadIdx.x;         // 64 threads
    float v = (t < NUM_CLASS) ? cls[t] : 0.f;
    #pragma unroll
    for (int off = 32; off > 0; off >>= 1) v += __shfl_down(v, off);
    if (t == 0) {
        const float emb = v / (float)NUM_CLASS;
        out[0] = 1.0f * expf(-2.0f * emb);     // ALPHA * exp(-GAMMA * emb)
    }
}

extern "C" void kernel_launch(void* const* d_in, const int* in_sizes, int n_in,
                              void* d_out, int out_size, void* d_ws, size_t ws_size,
                              hipStream_t stream)
{
    const float* feat = (const float*)d_in[0];
    const float* mask = (const float*)d_in[1];
    float* out = (float*)d_out;

    const size_t per_blk = (size_t)(NUM_CLASS * D_DIM + NUM_CLASS) * sizeof(float);
    int G = MAX_GRID;
    size_t need = (size_t)G * per_blk + NUM_CLASS * sizeof(float);
    if (ws_size < need) {
        size_t g = (ws_size > NUM_CLASS * sizeof(float))
                       ? (ws_size - NUM_CLASS * sizeof(float)) / per_blk : 1;
        if (g < 1) g = 1;
        if (g > MAX_GRID) g = MAX_GRID;
        G = (int)g;
    }
    float* part  = (float*)d_ws;
    float* npart = part + (size_t)G * (NUM_CLASS * D_DIM);
    float* cls   = npart + (size_t)G * NUM_CLASS;

    emb_main<<<G, BLOCK_THREADS, 0, stream>>>(feat, mask, part, npart, G);
    emb_reduce<<<NUM_CLASS, 1024, 0, stream>>>(part, npart, cls, G);
    emb_final<<<1, 64, 0, stream>>>(cls, out);
}